// Round 1
// baseline (474.613 us; speedup 1.0000x reference)
//
#include <hip/hip_runtime.h>

typedef unsigned short u16;
typedef unsigned int u32;
typedef __attribute__((ext_vector_type(8))) short short8;   // 8 bf16 = 4 VGPR MFMA operand
typedef __attribute__((ext_vector_type(4))) float f32x4;

#define MFMA(a, b, c) __builtin_amdgcn_mfma_f32_16x16x32_bf16((a), (b), (c), 0, 0, 0)

static __device__ __forceinline__ u16 f2bf(float f) {
  u32 u = __float_as_uint(f);
  u32 r = (u + 0x7FFFu + ((u >> 16) & 1u)) >> 16;   // RNE
  return (u16)r;
}
static __device__ __forceinline__ float bf2f(u16 s) {
  return __uint_as_float(((u32)s) << 16);
}
static __device__ __forceinline__ void gload16(const void* g, void* l) {
  __builtin_amdgcn_global_load_lds(
      (const __attribute__((address_space(1))) void*)g,
      (__attribute__((address_space(3))) void*)l, 16, 0, 0);
}
// swizzled LDS read: rows are 128B; physical col = col ^ ((row&7)<<4)  (T2 st-style swizzle)
static __device__ __forceinline__ short8 lds8(const u16* base, int row, int colb) {
  int phys = row * 128 + (colb ^ ((row & 7) << 4));
  return *(const short8*)((const char*)base + phys);
}

// ---------------- split: fp32 -> bf16 hi/lo ----------------
__global__ void split_kernel(const float* __restrict__ in, u16* __restrict__ hi,
                             u16* __restrict__ lo, int n4) {
  int i = blockIdx.x * blockDim.x + threadIdx.x;
  int stride = gridDim.x * blockDim.x;
  for (; i < n4; i += stride) {
    float4 v = ((const float4*)in)[i];
    ushort4 h, l;
    h.x = f2bf(v.x); l.x = f2bf(v.x - bf2f(h.x));
    h.y = f2bf(v.y); l.y = f2bf(v.y - bf2f(h.y));
    h.z = f2bf(v.z); l.z = f2bf(v.z - bf2f(h.z));
    h.w = f2bf(v.w); l.w = f2bf(v.w - bf2f(h.w));
    ((ushort4*)hi)[i] = h;
    ((ushort4*)lo)[i] = l;
  }
}

// ---------------- QKV projection GEMM ----------------
// C[8192][3072] = X[8192][1024] @ W[3072][1024]^T + b   (NT, hi/lo 3-product for q/k cols)
// grid (24, 64): x = col tile (128 cols), y = row tile (128 rows). 256 thr = 4 waves (2x2).
__global__ __launch_bounds__(256, 2) void gemm_qkv(
    const u16* __restrict__ xh, const u16* __restrict__ xl,
    const u16* __restrict__ wh, const u16* __restrict__ wl,
    const float* __restrict__ bias,
    u16* __restrict__ qkh, u16* __restrict__ qkl, u16* __restrict__ vt) {
  __shared__ __align__(16) u16 sAh[128 * 64];
  __shared__ __align__(16) u16 sAl[128 * 64];
  __shared__ __align__(16) u16 sBh[128 * 64];
  __shared__ __align__(16) u16 sBl[128 * 64];
  const int ct = blockIdx.x, mt = blockIdx.y;
  const int c0 = ct * 128, m0 = mt * 128;
  const bool isV = (ct >= 16);
  const int tid = threadIdx.x, lane = tid & 63, w = tid >> 6;
  const int wm = w >> 1, wn = w & 1;
  f32x4 acc[4][4] = {};

  for (int t = 0; t < 16; ++t) {
    const int k0 = t * 64;
    // stage 16KB per array; wave w stages chunks w*4..w*4+3 (1KB each = 8 rows of 128B)
    for (int j = 0; j < 4; ++j) {
      int chunk = w * 4 + j;
      int r = chunk * 8 + (lane >> 3);
      int cb = (lane & 7) * 16;
      int cbs = cb ^ ((r & 7) << 4);    // inverse-swizzled global source, linear LDS dest
      gload16((const char*)(xh + (size_t)(m0 + r) * 1024 + k0) + cbs, (char*)sAh + chunk * 1024);
      gload16((const char*)(wh + (size_t)(c0 + r) * 1024 + k0) + cbs, (char*)sBh + chunk * 1024);
      if (!isV) {
        gload16((const char*)(xl + (size_t)(m0 + r) * 1024 + k0) + cbs, (char*)sAl + chunk * 1024);
        gload16((const char*)(wl + (size_t)(c0 + r) * 1024 + k0) + cbs, (char*)sBl + chunk * 1024);
      }
    }
    asm volatile("s_waitcnt vmcnt(0)" ::: "memory");
    __syncthreads();

    for (int ki = 0; ki < 2; ++ki) {
      const int colb = (ki * 32 + (lane >> 4) * 8) * 2;
      short8 ah[4], al[4], bh[4], bl[4];
      for (int mi = 0; mi < 4; ++mi) {
        int row = wm * 64 + mi * 16 + (lane & 15);
        ah[mi] = lds8(sAh, row, colb);
        if (!isV) al[mi] = lds8(sAl, row, colb);
      }
      for (int ni = 0; ni < 4; ++ni) {
        int row = wn * 64 + ni * 16 + (lane & 15);
        bh[ni] = lds8(sBh, row, colb);
        if (!isV) bl[ni] = lds8(sBl, row, colb);
      }
      for (int mi = 0; mi < 4; ++mi)
        for (int ni = 0; ni < 4; ++ni) {
          acc[mi][ni] = MFMA(ah[mi], bh[ni], acc[mi][ni]);
          if (!isV) {
            acc[mi][ni] = MFMA(ah[mi], bl[ni], acc[mi][ni]);
            acc[mi][ni] = MFMA(al[mi], bh[ni], acc[mi][ni]);
          }
        }
    }
    __syncthreads();
  }

  // epilogue: bias + hi/lo store (q/k) or transposed bf16 store (v)
  const int g = lane >> 4, cl = lane & 15;
  for (int ni = 0; ni < 4; ++ni) {
    const int c = c0 + wn * 64 + ni * 16 + cl;
    const float bv = bias[c];
    for (int mi = 0; mi < 4; ++mi) {
      for (int i = 0; i < 4; ++i) {
        int m = m0 + wm * 64 + mi * 16 + g * 4 + i;
        float v = acc[mi][ni][i] + bv;
        if (!isV) {
          u16 h16 = f2bf(v);
          qkh[(size_t)m * 2048 + c] = h16;
          qkl[(size_t)m * 2048 + c] = f2bf(v - bf2f(h16));
        } else {
          int cv = c - 2048, hh = cv >> 6, p = cv & 63;
          int b = m >> 11, n = m & 2047;
          vt[((size_t)(b * 16 + hh) * 64 + p) * 2048 + n] = f2bf(v);
        }
      }
    }
  }
}

// ---------------- flash attention ----------------
// grid (16, 64): x = q tile (128 rows), y = bh. 256 thr = 4 waves, each 32 q-rows.
__global__ __launch_bounds__(256, 2) void attn_kernel(
    const u16* __restrict__ qkh, const u16* __restrict__ qkl,
    const u16* __restrict__ vt, float* __restrict__ out) {
  __shared__ __align__(16) union USm {
    struct { u16 kh[4096]; u16 kl[4096]; u16 vtt[4096]; u16 p[4][32 * 72]; } s;
    struct { u16 qh[8192]; u16 ql[8192]; } q;
  } sm;

  const int tid = threadIdx.x, lane = tid & 63, w = tid >> 6;
  const int qt = blockIdx.x, bh = blockIdx.y;
  const int b = bh >> 4, h = bh & 15;
  const int q0 = qt * 128;
  const size_t rowbase = (size_t)b * 2048;

  // stage Q hi/lo [128][64]
  for (int j = 0; j < 4; ++j) {
    int chunk = w * 4 + j;
    int r = chunk * 8 + (lane >> 3);
    int cb = (lane & 7) * 16;
    int cbs = cb ^ ((r & 7) << 4);
    gload16((const char*)(qkh + (rowbase + q0 + r) * 2048 + h * 64) + cbs, (char*)sm.q.qh + chunk * 1024);
    gload16((const char*)(qkl + (rowbase + q0 + r) * 2048 + h * 64) + cbs, (char*)sm.q.ql + chunk * 1024);
  }
  asm volatile("s_waitcnt vmcnt(0)" ::: "memory");
  __syncthreads();
  short8 qhf[2][2], qlf[2][2];
  for (int mi = 0; mi < 2; ++mi)
    for (int ki = 0; ki < 2; ++ki) {
      int row = w * 32 + mi * 16 + (lane & 15);
      int colb = (ki * 32 + (lane >> 4) * 8) * 2;
      qhf[mi][ki] = lds8(sm.q.qh, row, colb);
      qlf[mi][ki] = lds8(sm.q.ql, row, colb);
    }
  __syncthreads();   // Q regs extracted; LDS free for K/V

  f32x4 oacc[2][4] = {};
  float mrow[2][4], lrow[2][4];
  for (int mi = 0; mi < 2; ++mi)
    for (int i = 0; i < 4; ++i) { mrow[mi][i] = -3.0e38f; lrow[mi][i] = 0.f; }

  for (int t = 0; t < 32; ++t) {
    const int kv0 = t * 64;
    // stage Kh, Kl [64 kv][64 p] and V^T [64 p][64 kv]
    for (int j = 0; j < 2; ++j) {
      int chunk = w * 2 + j;
      int r = chunk * 8 + (lane >> 3);
      int cb = (lane & 7) * 16;
      int cbs = cb ^ ((r & 7) << 4);
      gload16((const char*)(qkh + (rowbase + kv0 + r) * 2048 + 1024 + h * 64) + cbs, (char*)sm.s.kh + chunk * 1024);
      gload16((const char*)(qkl + (rowbase + kv0 + r) * 2048 + 1024 + h * 64) + cbs, (char*)sm.s.kl + chunk * 1024);
      gload16((const char*)(vt + ((size_t)bh * 64 + r) * 2048 + kv0) + cbs, (char*)sm.s.vtt + chunk * 1024);
    }
    asm volatile("s_waitcnt vmcnt(0)" ::: "memory");
    __syncthreads();

    // S = Q K^T  (3-product hi/lo)
    f32x4 sacc[2][4] = {};
    for (int ki = 0; ki < 2; ++ki) {
      const int colb = (ki * 32 + (lane >> 4) * 8) * 2;
      short8 khf[4], klf[4];
      for (int ni = 0; ni < 4; ++ni) {
        int row = ni * 16 + (lane & 15);
        khf[ni] = lds8(sm.s.kh, row, colb);
        klf[ni] = lds8(sm.s.kl, row, colb);
      }
      for (int mi = 0; mi < 2; ++mi)
        for (int ni = 0; ni < 4; ++ni) {
          sacc[mi][ni] = MFMA(qhf[mi][ki], khf[ni], sacc[mi][ni]);
          sacc[mi][ni] = MFMA(qhf[mi][ki], klf[ni], sacc[mi][ni]);
          sacc[mi][ni] = MFMA(qlf[mi][ki], khf[ni], sacc[mi][ni]);
        }
    }
    // online softmax (rows spread over 16-lane groups; 4 rows per lane as acc regs)
    for (int mi = 0; mi < 2; ++mi)
      for (int i = 0; i < 4; ++i) {
        float mx = fmaxf(fmaxf(sacc[mi][0][i], sacc[mi][1][i]),
                         fmaxf(sacc[mi][2][i], sacc[mi][3][i]));
        mx = fmaxf(mx, __shfl_xor(mx, 1));
        mx = fmaxf(mx, __shfl_xor(mx, 2));
        mx = fmaxf(mx, __shfl_xor(mx, 4));
        mx = fmaxf(mx, __shfl_xor(mx, 8));
        float mnew = fmaxf(mrow[mi][i], mx);
        float corr = __expf(mrow[mi][i] - mnew);
        mrow[mi][i] = mnew;
        float rs = 0.f;
        int prow = mi * 16 + (lane >> 4) * 4 + i;
        for (int ni = 0; ni < 4; ++ni) {
          float p = __expf(sacc[mi][ni][i] - mnew);
          rs += p;
          sm.s.p[w][prow * 72 + ni * 16 + (lane & 15)] = f2bf(p);
        }
        rs += __shfl_xor(rs, 1);
        rs += __shfl_xor(rs, 2);
        rs += __shfl_xor(rs, 4);
        rs += __shfl_xor(rs, 8);
        lrow[mi][i] = lrow[mi][i] * corr + rs;
        for (int ni = 0; ni < 4; ++ni) oacc[mi][ni][i] *= corr;
      }
    __syncthreads();   // P visible (and K reads done)

    // O += P V
    for (int ki = 0; ki < 2; ++ki) {
      const int cp = ki * 32 + (lane >> 4) * 8;
      short8 pf[2];
      for (int mi = 0; mi < 2; ++mi) {
        int row = mi * 16 + (lane & 15);
        pf[mi] = *(const short8*)&sm.s.p[w][row * 72 + cp];
      }
      for (int ni = 0; ni < 4; ++ni) {
        short8 vf = lds8(sm.s.vtt, ni * 16 + (lane & 15), cp * 2);
        for (int mi = 0; mi < 2; ++mi) oacc[mi][ni] = MFMA(pf[mi], vf, oacc[mi][ni]);
      }
    }
    __syncthreads();   // done with K/V/P before next stage
  }

  // epilogue: O / l  -> out in faithful (B,H,N,pd) flat layout, fp32
  for (int mi = 0; mi < 2; ++mi)
    for (int i = 0; i < 4; ++i) {
      float inv = 1.f / lrow[mi][i];
      int grow = q0 + w * 32 + mi * 16 + (lane >> 4) * 4 + i;
      size_t obase = ((size_t)bh * 2048 + grow) * 64;
      for (int ni = 0; ni < 4; ++ni)
        out[obase + ni * 16 + (lane & 15)] = oacc[mi][ni][i] * inv;
    }
}

extern "C" void kernel_launch(void* const* d_in, const int* in_sizes, int n_in,
                              void* d_out, int out_size, void* d_ws, size_t ws_size,
                              hipStream_t stream) {
  (void)in_sizes; (void)n_in; (void)out_size; (void)ws_size;
  const float* x = (const float*)d_in[0];
  const float* Wqkv = (const float*)d_in[1];
  const float* bqkv = (const float*)d_in[2];
  float* out = (float*)d_out;

  u16* xh  = (u16*)d_ws;                 // [8192][1024]
  u16* xl  = xh + 8388608;
  u16* wh  = xl + 8388608;               // [3072][1024]
  u16* wl  = wh + 3145728;
  u16* qkh = wl + 3145728;               // [8192][2048]  (q cols 0..1023, k cols 1024..2047)
  u16* qkl = qkh + 16777216;
  u16* vtb = qkl + 16777216;             // [64][64][2048] = vt[bh][p][n]

  split_kernel<<<2048, 256, 0, stream>>>(x, xh, xl, 8388608 / 4);
  split_kernel<<<768, 256, 0, stream>>>(Wqkv, wh, wl, 3145728 / 4);
  gemm_qkv<<<dim3(24, 64), 256, 0, stream>>>(xh, xl, wh, wl, bqkv, qkh, qkl, vtb);
  attn_kernel<<<dim3(16, 64), 256, 0, stream>>>(qkh, qkl, vtb, out);
}

// Round 3
// 452.139 us; speedup vs baseline: 1.0497x; 1.0497x over previous
//
#include <hip/hip_runtime.h>

typedef unsigned short u16;
typedef unsigned int u32;
typedef __attribute__((ext_vector_type(8))) short short8;   // 8 bf16 = 4 VGPR MFMA operand
typedef __attribute__((ext_vector_type(4))) float f32x4;

#define MFMA(a, b, c) __builtin_amdgcn_mfma_f32_16x16x32_bf16((a), (b), (c), 0, 0, 0)

static __device__ __forceinline__ u16 f2bf(float f) {
  u32 u = __float_as_uint(f);
  u32 r = (u + 0x7FFFu + ((u >> 16) & 1u)) >> 16;   // RNE
  return (u16)r;
}
static __device__ __forceinline__ float bf2f(u16 s) {
  return __uint_as_float(((u32)s) << 16);
}
static __device__ __forceinline__ void gload16(const void* g, void* l) {
  __builtin_amdgcn_global_load_lds(
      (const __attribute__((address_space(1))) void*)g,
      (__attribute__((address_space(3))) void*)l, 16, 0, 0);
}
// swizzled LDS read: rows are 128B; physical col = col ^ ((row&7)<<4)  (T2 st-style swizzle)
static __device__ __forceinline__ short8 lds8(const u16* base, int row, int colb) {
  int phys = row * 128 + (colb ^ ((row & 7) << 4));
  return *(const short8*)((const char*)base + phys);
}

// ---------------- split: fp32 -> bf16 hi/lo ----------------
__global__ void split_kernel(const float* __restrict__ in, u16* __restrict__ hi,
                             u16* __restrict__ lo, int n4) {
  int i = blockIdx.x * blockDim.x + threadIdx.x;
  int stride = gridDim.x * blockDim.x;
  for (; i < n4; i += stride) {
    float4 v = ((const float4*)in)[i];
    ushort4 h, l;
    h.x = f2bf(v.x); l.x = f2bf(v.x - bf2f(h.x));
    h.y = f2bf(v.y); l.y = f2bf(v.y - bf2f(h.y));
    h.z = f2bf(v.z); l.z = f2bf(v.z - bf2f(h.z));
    h.w = f2bf(v.w); l.w = f2bf(v.w - bf2f(h.w));
    ((ushort4*)hi)[i] = h;
    ((ushort4*)lo)[i] = l;
  }
}

// ---------------- QKV projection GEMM ----------------
// C[8192][3072] = X[8192][1024] @ W[3072][1024]^T + b   (NT, hi/lo 3-product for q/k cols)
// Epilogue writes Q/K (hi/lo) and V in MFMA-fragment-ready layout
// [bh][t(32)][ki(2)][ni(4)][lane(64)][e(8)] so attn loads fragments coalesced, no LDS staging.
// grid (24, 64): x = col tile (128 cols), y = row tile (128 rows). 256 thr = 4 waves (2x2).
__global__ __launch_bounds__(256, 2) void gemm_qkv(
    const u16* __restrict__ xh, const u16* __restrict__ xl,
    const u16* __restrict__ wh, const u16* __restrict__ wl,
    const float* __restrict__ bias,
    u16* __restrict__ qfh, u16* __restrict__ qfl,
    u16* __restrict__ kfh, u16* __restrict__ kfl, u16* __restrict__ vfp) {
  __shared__ __align__(16) u16 sAh[128 * 64];
  __shared__ __align__(16) u16 sAl[128 * 64];
  __shared__ __align__(16) u16 sBh[128 * 64];
  __shared__ __align__(16) u16 sBl[128 * 64];
  const int ct = blockIdx.x, mt = blockIdx.y;
  const int c0 = ct * 128, m0 = mt * 128;
  const bool isV = (ct >= 16);
  const int tid = threadIdx.x, lane = tid & 63, w = tid >> 6;
  const int wm = w >> 1, wn = w & 1;
  f32x4 acc[4][4] = {};

  for (int t = 0; t < 16; ++t) {
    const int k0 = t * 64;
    for (int j = 0; j < 4; ++j) {
      int chunk = w * 4 + j;
      int r = chunk * 8 + (lane >> 3);
      int cb = (lane & 7) * 16;
      int cbs = cb ^ ((r & 7) << 4);    // inverse-swizzled global source, linear LDS dest
      gload16((const char*)(xh + (size_t)(m0 + r) * 1024 + k0) + cbs, (char*)sAh + chunk * 1024);
      gload16((const char*)(wh + (size_t)(c0 + r) * 1024 + k0) + cbs, (char*)sBh + chunk * 1024);
      if (!isV) {
        gload16((const char*)(xl + (size_t)(m0 + r) * 1024 + k0) + cbs, (char*)sAl + chunk * 1024);
        gload16((const char*)(wl + (size_t)(c0 + r) * 1024 + k0) + cbs, (char*)sBl + chunk * 1024);
      }
    }
    asm volatile("s_waitcnt vmcnt(0)" ::: "memory");
    __syncthreads();

    for (int ki = 0; ki < 2; ++ki) {
      const int colb = (ki * 32 + (lane >> 4) * 8) * 2;
      short8 ah[4], al[4], bh[4], bl[4];
      for (int mi = 0; mi < 4; ++mi) {
        int row = wm * 64 + mi * 16 + (lane & 15);
        ah[mi] = lds8(sAh, row, colb);
        if (!isV) al[mi] = lds8(sAl, row, colb);
      }
      for (int ni = 0; ni < 4; ++ni) {
        int row = wn * 64 + ni * 16 + (lane & 15);
        bh[ni] = lds8(sBh, row, colb);
        if (!isV) bl[ni] = lds8(sBl, row, colb);
      }
      for (int mi = 0; mi < 4; ++mi)
        for (int ni = 0; ni < 4; ++ni) {
          acc[mi][ni] = MFMA(ah[mi], bh[ni], acc[mi][ni]);
          if (!isV) {
            acc[mi][ni] = MFMA(ah[mi], bl[ni], acc[mi][ni]);
            acc[mi][ni] = MFMA(al[mi], bh[ni], acc[mi][ni]);
          }
        }
    }
    __syncthreads();
  }

  // epilogue: bias + fragment-layout stores
  const int g = lane >> 4, cl = lane & 15;
  const int b = m0 >> 11;
  const int n0t = (m0 & 2047) >> 6;
  const int t = n0t + wm;                 // 64-row tile index within the sequence
  if (!isV) {
    for (int ni = 0; ni < 4; ++ni) {
      const int c = c0 + wn * 64 + ni * 16 + cl;
      const float bv = bias[c];
      u16* dh = (c < 1024) ? qfh : kfh;
      u16* dl = (c < 1024) ? qfl : kfl;
      const int p = c & 63, h = (c & 1023) >> 6;
      const int kki = p >> 5, lhi = (p >> 3) & 3, e = p & 7;
      for (int mi = 0; mi < 4; ++mi) {
        // A/B-operand layout: row-in-tile = mi(ni-slot)*16 + lane_lo, elems along p
        size_t base = (((size_t)(b * 16 + h) * 32 + t) * 8 + (size_t)kki * 4 + mi) * 512
                      + (size_t)lhi * 128 + e;
        for (int i = 0; i < 4; ++i) {
          float v = acc[mi][ni][i] + bv;
          u16 h16 = f2bf(v);
          dh[base + (size_t)(g * 4 + i) * 8] = h16;
          dl[base + (size_t)(g * 4 + i) * 8] = f2bf(v - bf2f(h16));
        }
      }
    }
  } else {
    for (int ni = 0; ni < 4; ++ni) {
      const int c = c0 + wn * 64 + ni * 16 + cl;
      const float bv = bias[c];
      const int cv = c - 2048, h = cv >> 6, p = cv & 63;
      const int niv = p >> 4, lane_lo = p & 15;
      for (int mi = 0; mi < 4; ++mi) {
        const int kki = mi >> 1;
        for (int i = 0; i < 4; ++i) {
          // B-operand layout for PV: row = p, elems along kv
          const int lhi = (mi & 1) * 2 + (g >> 1);
          const int e = (g & 1) * 4 + i;
          size_t a = (((size_t)(b * 16 + h) * 32 + t) * 8 + (size_t)kki * 4 + niv) * 512
                     + (size_t)(lhi * 16 + lane_lo) * 8 + e;
          vfp[a] = f2bf(acc[mi][ni][i] + bv);
        }
      }
    }
  }
}

// ---------------- flash attention (barrier-free) ----------------
// grid (16, 64): x = q tile (128 rows), y = bh. 256 thr = 4 waves, each 32 q-rows.
// All K/V fragments loaded coalesced from global (L2-resident); only LDS use is the
// per-wave P transpose buffer -> NO __syncthreads anywhere.
__global__ __launch_bounds__(256, 2) void attn_kernel(
    const u16* __restrict__ qfh, const u16* __restrict__ qfl,
    const u16* __restrict__ kfh, const u16* __restrict__ kfl,
    const u16* __restrict__ vfp, float* __restrict__ out) {
  __shared__ __align__(16) u16 pbuf[4][32 * 72];

  const int tid = threadIdx.x, lane = tid & 63, w = tid >> 6;
  const int qt = blockIdx.x, bh = blockIdx.y;
  const size_t bhbase = (size_t)bh * 32 * 4096;   // per t: 2ki*4ni*512 = 4096 u16

  // Q fragments (hi/lo), straight from fragment layout
  short8 qhf[2][2], qlf[2][2];
  for (int mi = 0; mi < 2; ++mi) {
    int idx = 2 * w + mi;
    int t = qt * 2 + (idx >> 2), nni = idx & 3;
    for (int ki = 0; ki < 2; ++ki) {
      size_t a = bhbase + (((size_t)t * 2 + ki) * 4 + nni) * 512 + (size_t)lane * 8;
      qhf[mi][ki] = *(const short8*)(qfh + a);
      qlf[mi][ki] = *(const short8*)(qfl + a);
    }
  }

  f32x4 oacc[2][4] = {};
  float mrow[2][4], lrow[2][4];
  for (int mi = 0; mi < 2; ++mi)
    for (int i = 0; i < 4; ++i) { mrow[mi][i] = -3.0e38f; lrow[mi][i] = 0.f; }

  for (int t = 0; t < 32; ++t) {
    const size_t tb = bhbase + (size_t)t * 4096;

    // S = Q K^T  (3-product hi/lo), K fragments direct from global
    f32x4 sacc[2][4] = {};
    for (int ki = 0; ki < 2; ++ki) {
      short8 khf[4], klf[4];
      for (int ni = 0; ni < 4; ++ni) {
        size_t a = tb + (((size_t)ki * 4 + ni) * 64 + lane) * 8;
        khf[ni] = *(const short8*)(kfh + a);
        klf[ni] = *(const short8*)(kfl + a);
      }
      for (int mi = 0; mi < 2; ++mi)
        for (int ni = 0; ni < 4; ++ni) {
          sacc[mi][ni] = MFMA(qhf[mi][ki], khf[ni], sacc[mi][ni]);
          sacc[mi][ni] = MFMA(qhf[mi][ki], klf[ni], sacc[mi][ni]);
          sacc[mi][ni] = MFMA(qlf[mi][ki], khf[ni], sacc[mi][ni]);
        }
    }

    // issue V fragment loads now; latency hides under softmax VALU
    short8 vfr[2][4];
    for (int ki = 0; ki < 2; ++ki)
      for (int ni = 0; ni < 4; ++ni)
        vfr[ki][ni] = *(const short8*)(vfp + tb + (((size_t)ki * 4 + ni) * 64 + lane) * 8);

    // online softmax (rows spread over 16-lane groups; 4 rows per lane as acc regs)
    for (int mi = 0; mi < 2; ++mi)
      for (int i = 0; i < 4; ++i) {
        float mx = fmaxf(fmaxf(sacc[mi][0][i], sacc[mi][1][i]),
                         fmaxf(sacc[mi][2][i], sacc[mi][3][i]));
        mx = fmaxf(mx, __shfl_xor(mx, 1));
        mx = fmaxf(mx, __shfl_xor(mx, 2));
        mx = fmaxf(mx, __shfl_xor(mx, 4));
        mx = fmaxf(mx, __shfl_xor(mx, 8));
        float mnew = fmaxf(mrow[mi][i], mx);
        float corr = __expf(mrow[mi][i] - mnew);
        mrow[mi][i] = mnew;
        float rs = 0.f;
        int prow = mi * 16 + (lane >> 4) * 4 + i;
        for (int ni = 0; ni < 4; ++ni) {
          float p = __expf(sacc[mi][ni][i] - mnew);
          rs += p;
          pbuf[w][prow * 72 + ni * 16 + (lane & 15)] =
              (u16)((__float_as_uint(p) + 0x8000u) >> 16);   // cheap nearest
        }
        rs += __shfl_xor(rs, 1);
        rs += __shfl_xor(rs, 2);
        rs += __shfl_xor(rs, 4);
        rs += __shfl_xor(rs, 8);
        lrow[mi][i] = lrow[mi][i] * corr + rs;
        for (int ni = 0; ni < 4; ++ni) oacc[mi][ni][i] *= corr;
      }

    // O += P V   (P transposed through per-wave LDS; same-wave -> lgkmcnt only)
    for (int ki = 0; ki < 2; ++ki) {
      const int cp = ki * 32 + (lane >> 4) * 8;
      short8 pf[2];
      for (int mi = 0; mi < 2; ++mi) {
        int row = mi * 16 + (lane & 15);
        pf[mi] = *(const short8*)&pbuf[w][row * 72 + cp];
      }
      for (int ni = 0; ni < 4; ++ni)
        for (int mi = 0; mi < 2; ++mi)
          oacc[mi][ni] = MFMA(pf[mi], vfr[ki][ni], oacc[mi][ni]);
    }
  }

  // epilogue: O / l  -> out in faithful (B,H,N,pd) flat layout, fp32
  for (int mi = 0; mi < 2; ++mi)
    for (int i = 0; i < 4; ++i) {
      float inv = 1.f / lrow[mi][i];
      int grow = qt * 128 + w * 32 + mi * 16 + (lane >> 4) * 4 + i;
      size_t obase = ((size_t)bh * 2048 + grow) * 64;
      for (int ni = 0; ni < 4; ++ni)
        out[obase + ni * 16 + (lane & 15)] = oacc[mi][ni][i] * inv;
    }
}

extern "C" void kernel_launch(void* const* d_in, const int* in_sizes, int n_in,
                              void* d_out, int out_size, void* d_ws, size_t ws_size,
                              hipStream_t stream) {
  (void)in_sizes; (void)n_in; (void)out_size; (void)ws_size;
  const float* x = (const float*)d_in[0];
  const float* Wqkv = (const float*)d_in[1];
  const float* bqkv = (const float*)d_in[2];
  float* out = (float*)d_out;

  u16* xh  = (u16*)d_ws;                 // [8192][1024]
  u16* xl  = xh + 8388608;
  u16* wh  = xl + 8388608;               // [3072][1024]
  u16* wl  = wh + 3145728;
  u16* qfh = wl + 3145728;               // fragment layouts: [bh][t][ki][ni][lane][8]
  u16* qfl = qfh + 8388608;
  u16* kfh = qfl + 8388608;
  u16* kfl = kfh + 8388608;
  u16* vfp = kfl + 8388608;
  // total ws use: 130 MB (same as passing R1 layout)

  split_kernel<<<2048, 256, 0, stream>>>(x, xh, xl, 8388608 / 4);
  split_kernel<<<768, 256, 0, stream>>>(Wqkv, wh, wl, 3145728 / 4);
  gemm_qkv<<<dim3(24, 64), 256, 0, stream>>>(xh, xl, wh, wl, bqkv, qfh, qfl, kfh, kfl, vfp);
  attn_kernel<<<dim3(16, 64), 256, 0, stream>>>(qfh, qfl, kfh, kfl, vfp, out);
}

// Round 4
// 448.020 us; speedup vs baseline: 1.0594x; 1.0092x over previous
//
#include <hip/hip_runtime.h>

typedef unsigned short u16;
typedef unsigned int u32;
typedef __attribute__((ext_vector_type(8))) short short8;   // 8 bf16 = 4 VGPR MFMA operand
typedef __attribute__((ext_vector_type(4))) float f32x4;

#define MFMA(a, b, c) __builtin_amdgcn_mfma_f32_16x16x32_bf16((a), (b), (c), 0, 0, 0)

static __device__ __forceinline__ u16 f2bf(float f) {
  u32 u = __float_as_uint(f);
  u32 r = (u + 0x7FFFu + ((u >> 16) & 1u)) >> 16;   // RNE
  return (u16)r;
}
static __device__ __forceinline__ float bf2f(u16 s) {
  return __uint_as_float(((u32)s) << 16);
}
static __device__ __forceinline__ void gload16(const void* g, void* l) {
  __builtin_amdgcn_global_load_lds(
      (const __attribute__((address_space(1))) void*)g,
      (__attribute__((address_space(3))) void*)l, 16, 0, 0);
}
// swizzled LDS read: rows are 128B; physical col = col ^ ((row&7)<<4)  (T2 st-style swizzle)
static __device__ __forceinline__ short8 lds8(const u16* base, int row, int colb) {
  int phys = row * 128 + (colb ^ ((row & 7) << 4));
  return *(const short8*)((const char*)base + phys);
}

// ---------------- split: fp32 -> bf16 hi/lo ----------------
__global__ void split_kernel(const float* __restrict__ in, u16* __restrict__ hi,
                             u16* __restrict__ lo, int n4) {
  int i = blockIdx.x * blockDim.x + threadIdx.x;
  int stride = gridDim.x * blockDim.x;
  for (; i < n4; i += stride) {
    float4 v = ((const float4*)in)[i];
    ushort4 h, l;
    h.x = f2bf(v.x); l.x = f2bf(v.x - bf2f(h.x));
    h.y = f2bf(v.y); l.y = f2bf(v.y - bf2f(h.y));
    h.z = f2bf(v.z); l.z = f2bf(v.z - bf2f(h.z));
    h.w = f2bf(v.w); l.w = f2bf(v.w - bf2f(h.w));
    ((ushort4*)hi)[i] = h;
    ((ushort4*)lo)[i] = l;
  }
}

// ---------------- QKV projection GEMM ----------------
// C[8192][3072] = X[8192][1024] @ W[3072][1024]^T + b   (NT, hi/lo 3-product for q/k cols)
// Launched 1-D (1536 blocks); bijective XCD swizzle (T1/m204, 1536%8==0) so each XCD
// owns 8 consecutive row-panels (mt) -> A-panel reuse is L2-local.
__global__ __launch_bounds__(256, 2) void gemm_qkv(
    const u16* __restrict__ xh, const u16* __restrict__ xl,
    const u16* __restrict__ wh, const u16* __restrict__ wl,
    const float* __restrict__ bias,
    u16* __restrict__ qfh, u16* __restrict__ qfl,
    u16* __restrict__ kfh, u16* __restrict__ kfl, u16* __restrict__ vfp) {
  __shared__ __align__(16) u16 sAh[128 * 64];
  __shared__ __align__(16) u16 sAl[128 * 64];
  __shared__ __align__(16) u16 sBh[128 * 64];
  __shared__ __align__(16) u16 sBl[128 * 64];
  const int L = blockIdx.x;
  const int swz = (L & 7) * 192 + (L >> 3);   // 1536/8 = 192; bijective
  const int ct = swz % 24, mt = swz / 24;
  const int c0 = ct * 128, m0 = mt * 128;
  const bool isV = (ct >= 16);
  const int tid = threadIdx.x, lane = tid & 63, w = tid >> 6;
  const int wm = w >> 1, wn = w & 1;
  f32x4 acc[4][4] = {};

  for (int t = 0; t < 16; ++t) {
    const int k0 = t * 64;
    for (int j = 0; j < 4; ++j) {
      int chunk = w * 4 + j;
      int r = chunk * 8 + (lane >> 3);
      int cb = (lane & 7) * 16;
      int cbs = cb ^ ((r & 7) << 4);    // inverse-swizzled global source, linear LDS dest
      gload16((const char*)(xh + (size_t)(m0 + r) * 1024 + k0) + cbs, (char*)sAh + chunk * 1024);
      gload16((const char*)(wh + (size_t)(c0 + r) * 1024 + k0) + cbs, (char*)sBh + chunk * 1024);
      if (!isV) {
        gload16((const char*)(xl + (size_t)(m0 + r) * 1024 + k0) + cbs, (char*)sAl + chunk * 1024);
        gload16((const char*)(wl + (size_t)(c0 + r) * 1024 + k0) + cbs, (char*)sBl + chunk * 1024);
      }
    }
    asm volatile("s_waitcnt vmcnt(0)" ::: "memory");
    __syncthreads();

    for (int ki = 0; ki < 2; ++ki) {
      const int colb = (ki * 32 + (lane >> 4) * 8) * 2;
      short8 ah[4], al[4], bh[4], bl[4];
      for (int mi = 0; mi < 4; ++mi) {
        int row = wm * 64 + mi * 16 + (lane & 15);
        ah[mi] = lds8(sAh, row, colb);
        if (!isV) al[mi] = lds8(sAl, row, colb);
      }
      for (int ni = 0; ni < 4; ++ni) {
        int row = wn * 64 + ni * 16 + (lane & 15);
        bh[ni] = lds8(sBh, row, colb);
        if (!isV) bl[ni] = lds8(sBl, row, colb);
      }
      for (int mi = 0; mi < 4; ++mi)
        for (int ni = 0; ni < 4; ++ni) {
          acc[mi][ni] = MFMA(ah[mi], bh[ni], acc[mi][ni]);
          if (!isV) {
            acc[mi][ni] = MFMA(ah[mi], bl[ni], acc[mi][ni]);
            acc[mi][ni] = MFMA(al[mi], bh[ni], acc[mi][ni]);
          }
        }
    }
    __syncthreads();
  }

  // epilogue: bias + fragment-layout stores
  const int g = lane >> 4, cl = lane & 15;
  const int b = m0 >> 11;
  const int n0t = (m0 & 2047) >> 6;
  const int t = n0t + wm;                 // 64-row tile index within the sequence
  if (!isV) {
    for (int ni = 0; ni < 4; ++ni) {
      const int c = c0 + wn * 64 + ni * 16 + cl;
      const float bv = bias[c];
      u16* dh = (c < 1024) ? qfh : kfh;
      u16* dl = (c < 1024) ? qfl : kfl;
      const int p = c & 63, h = (c & 1023) >> 6;
      const int kki = p >> 5, lhi = (p >> 3) & 3, e = p & 7;
      for (int mi = 0; mi < 4; ++mi) {
        // A/B-operand layout: row-in-tile = mi(ni-slot)*16 + lane_lo, elems along p
        size_t base = (((size_t)(b * 16 + h) * 32 + t) * 8 + (size_t)kki * 4 + mi) * 512
                      + (size_t)lhi * 128 + e;
        for (int i = 0; i < 4; ++i) {
          float v = acc[mi][ni][i] + bv;
          u16 h16 = f2bf(v);
          dh[base + (size_t)(g * 4 + i) * 8] = h16;
          dl[base + (size_t)(g * 4 + i) * 8] = f2bf(v - bf2f(h16));
        }
      }
    }
  } else {
    for (int ni = 0; ni < 4; ++ni) {
      const int c = c0 + wn * 64 + ni * 16 + cl;
      const float bv = bias[c];
      const int cv = c - 2048, h = cv >> 6, p = cv & 63;
      const int niv = p >> 4, lane_lo = p & 15;
      for (int mi = 0; mi < 4; ++mi) {
        const int kki = mi >> 1;
        for (int i = 0; i < 4; ++i) {
          // B-operand layout for PV: row = p, elems along kv
          const int lhi = (mi & 1) * 2 + (g >> 1);
          const int e = (g & 1) * 4 + i;
          size_t a = (((size_t)(b * 16 + h) * 32 + t) * 8 + (size_t)kki * 4 + niv) * 512
                     + (size_t)(lhi * 16 + lane_lo) * 8 + e;
          vfp[a] = f2bf(acc[mi][ni][i] + bv);
        }
      }
    }
  }
}

// ---------------- flash attention (barrier-free, XCD-colocated) ----------------
// 1024 blocks 1-D. Decode so all 16 qt-blocks of a bh land on ONE XCD (round-robin
// bid->XCD assumption): xcd = bid&7, bh = xcd*8 + ((bid>>3)>>4), qt = (bid>>3)&15.
// Per-XCD K/V working set then stays L2-resident; K/V fetched from HBM ~once.
__global__ __launch_bounds__(256, 2) void attn_kernel(
    const u16* __restrict__ qfh, const u16* __restrict__ qfl,
    const u16* __restrict__ kfh, const u16* __restrict__ kfl,
    const u16* __restrict__ vfp, float* __restrict__ out) {
  __shared__ __align__(16) u16 pbuf[4][32 * 72];

  const int tid = threadIdx.x, lane = tid & 63, w = tid >> 6;
  const int bid = blockIdx.x;
  const int xcd = bid & 7, li = bid >> 3;
  const int bh = xcd * 8 + (li >> 4);
  const int qt = li & 15;
  const size_t bhbase = (size_t)bh * 32 * 4096;   // per t: 2ki*4ni*512 = 4096 u16

  // Q fragments (hi/lo), straight from fragment layout
  short8 qhf[2][2], qlf[2][2];
  for (int mi = 0; mi < 2; ++mi) {
    int idx = 2 * w + mi;
    int t = qt * 2 + (idx >> 2), nni = idx & 3;
    for (int ki = 0; ki < 2; ++ki) {
      size_t a = bhbase + (((size_t)t * 2 + ki) * 4 + nni) * 512 + (size_t)lane * 8;
      qhf[mi][ki] = *(const short8*)(qfh + a);
      qlf[mi][ki] = *(const short8*)(qfl + a);
    }
  }

  f32x4 oacc[2][4] = {};
  float mrow[2][4], lrow[2][4];
  for (int mi = 0; mi < 2; ++mi)
    for (int i = 0; i < 4; ++i) { mrow[mi][i] = -3.0e38f; lrow[mi][i] = 0.f; }

  for (int t = 0; t < 32; ++t) {
    const size_t tb = bhbase + (size_t)t * 4096;

    // S = Q K^T  (3-product hi/lo), K fragments direct from global
    f32x4 sacc[2][4] = {};
    for (int ki = 0; ki < 2; ++ki) {
      short8 khf[4], klf[4];
      for (int ni = 0; ni < 4; ++ni) {
        size_t a = tb + (((size_t)ki * 4 + ni) * 64 + lane) * 8;
        khf[ni] = *(const short8*)(kfh + a);
        klf[ni] = *(const short8*)(kfl + a);
      }
      for (int mi = 0; mi < 2; ++mi)
        for (int ni = 0; ni < 4; ++ni) {
          sacc[mi][ni] = MFMA(qhf[mi][ki], khf[ni], sacc[mi][ni]);
          sacc[mi][ni] = MFMA(qhf[mi][ki], klf[ni], sacc[mi][ni]);
          sacc[mi][ni] = MFMA(qlf[mi][ki], khf[ni], sacc[mi][ni]);
        }
    }

    // issue V fragment loads now; latency hides under softmax VALU
    short8 vfr[2][4];
    for (int ki = 0; ki < 2; ++ki)
      for (int ni = 0; ni < 4; ++ni)
        vfr[ki][ni] = *(const short8*)(vfp + tb + (((size_t)ki * 4 + ni) * 64 + lane) * 8);

    // online softmax (rows spread over 16-lane groups; 4 rows per lane as acc regs)
    for (int mi = 0; mi < 2; ++mi)
      for (int i = 0; i < 4; ++i) {
        float mx = fmaxf(fmaxf(sacc[mi][0][i], sacc[mi][1][i]),
                         fmaxf(sacc[mi][2][i], sacc[mi][3][i]));
        mx = fmaxf(mx, __shfl_xor(mx, 1));
        mx = fmaxf(mx, __shfl_xor(mx, 2));
        mx = fmaxf(mx, __shfl_xor(mx, 4));
        mx = fmaxf(mx, __shfl_xor(mx, 8));
        float mnew = fmaxf(mrow[mi][i], mx);
        float corr = __expf(mrow[mi][i] - mnew);
        mrow[mi][i] = mnew;
        float rs = 0.f;
        int prow = mi * 16 + (lane >> 4) * 4 + i;
        for (int ni = 0; ni < 4; ++ni) {
          float p = __expf(sacc[mi][ni][i] - mnew);
          rs += p;
          pbuf[w][prow * 72 + ni * 16 + (lane & 15)] =
              (u16)((__float_as_uint(p) + 0x8000u) >> 16);   // cheap nearest
        }
        rs += __shfl_xor(rs, 1);
        rs += __shfl_xor(rs, 2);
        rs += __shfl_xor(rs, 4);
        rs += __shfl_xor(rs, 8);
        lrow[mi][i] = lrow[mi][i] * corr + rs;
        for (int ni = 0; ni < 4; ++ni) oacc[mi][ni][i] *= corr;
      }

    // O += P V   (P transposed through per-wave LDS; same-wave -> lgkmcnt only)
    for (int ki = 0; ki < 2; ++ki) {
      const int cp = ki * 32 + (lane >> 4) * 8;
      short8 pf[2];
      for (int mi = 0; mi < 2; ++mi) {
        int row = mi * 16 + (lane & 15);
        pf[mi] = *(const short8*)&pbuf[w][row * 72 + cp];
      }
      for (int ni = 0; ni < 4; ++ni)
        for (int mi = 0; mi < 2; ++mi)
          oacc[mi][ni] = MFMA(pf[mi], vfr[ki][ni], oacc[mi][ni]);
    }
  }

  // epilogue: O / l  -> out in faithful (B,H,N,pd) flat layout, fp32
  for (int mi = 0; mi < 2; ++mi)
    for (int i = 0; i < 4; ++i) {
      float inv = 1.f / lrow[mi][i];
      int grow = qt * 128 + w * 32 + mi * 16 + (lane >> 4) * 4 + i;
      size_t obase = ((size_t)bh * 2048 + grow) * 64;
      for (int ni = 0; ni < 4; ++ni)
        out[obase + ni * 16 + (lane & 15)] = oacc[mi][ni][i] * inv;
    }
}

extern "C" void kernel_launch(void* const* d_in, const int* in_sizes, int n_in,
                              void* d_out, int out_size, void* d_ws, size_t ws_size,
                              hipStream_t stream) {
  (void)in_sizes; (void)n_in; (void)out_size; (void)ws_size;
  const float* x = (const float*)d_in[0];
  const float* Wqkv = (const float*)d_in[1];
  const float* bqkv = (const float*)d_in[2];
  float* out = (float*)d_out;

  u16* xh  = (u16*)d_ws;                 // [8192][1024]
  u16* xl  = xh + 8388608;
  u16* wh  = xl + 8388608;               // [3072][1024]
  u16* wl  = wh + 3145728;
  u16* qfh = wl + 3145728;               // fragment layouts: [bh][t][ki][ni][lane][8]
  u16* qfl = qfh + 8388608;
  u16* kfh = qfl + 8388608;
  u16* kfl = kfh + 8388608;
  u16* vfp = kfl + 8388608;
  // total ws use: 130 MB (same as passing R1 layout)

  split_kernel<<<2048, 256, 0, stream>>>(x, xh, xl, 8388608 / 4);
  split_kernel<<<768, 256, 0, stream>>>(Wqkv, wh, wl, 3145728 / 4);
  gemm_qkv<<<1536, 256, 0, stream>>>(xh, xl, wh, wl, bqkv, qfh, qfl, kfh, kfl, vfp);
  attn_kernel<<<1024, 256, 0, stream>>>(qfh, qfl, kfh, kfl, vfp, out);
}